// Round 3
// baseline (305.233 us; speedup 1.0000x reference)
//
// GCN2 on MI355X — CSR-build + gather aggregation (zero float atomics). r2 resubmit (infra retry).
#include <hip/hip_runtime.h>
#include <math.h>

#define N_NODES 50000
#define N_EDGES 800000
#define D_FEAT 64

#define SCAN_CHUNK 256
#define SCAN_BLOCKS ((N_NODES + SCAN_CHUNK - 1) / SCAN_CHUNK)   // 196
#define AGG_BLOCKS (N_NODES / 4)                                 // 12500 (exact)
#define GEMM_BLOCKS (N_NODES / 16)                               // 3125 (exact)
#define EDGE_BLOCKS (N_EDGES / 256)                              // 3125 (exact)

// ---------------- CSR build ----------------

__global__ __launch_bounds__(256) void k_init(int* __restrict__ deg) {
    int i = blockIdx.x * 256 + threadIdx.x;
    if (i < N_NODES) deg[i] = 0;
}

__global__ __launch_bounds__(256) void k_hist(const int* __restrict__ dst,
                                              int* __restrict__ deg) {
    int e = blockIdx.x * 256 + threadIdx.x;   // grid exact
    atomicAdd(&deg[dst[e]], 1);
}

__global__ __launch_bounds__(256) void k_scan_part(const int* __restrict__ deg,
                                                   int* __restrict__ rowptr,
                                                   int* __restrict__ spart) {
    __shared__ int sh[256];
    int tid = threadIdx.x;
    int i = blockIdx.x * 256 + tid;
    int v = (i < N_NODES) ? deg[i] : 0;
    sh[tid] = v;
    __syncthreads();
    #pragma unroll
    for (int off = 1; off < 256; off <<= 1) {
        int t = (tid >= off) ? sh[tid - off] : 0;
        __syncthreads();
        sh[tid] += t;
        __syncthreads();
    }
    if (i < N_NODES) rowptr[i + 1] = sh[tid];
    if (tid == 255) spart[blockIdx.x] = sh[255];
    if (i == 0) rowptr[0] = 0;
}

__global__ __launch_bounds__(256) void k_scan_tops(int* __restrict__ spart) {
    __shared__ int sh[256];
    int tid = threadIdx.x;
    int v = (tid < SCAN_BLOCKS) ? spart[tid] : 0;
    sh[tid] = v;
    __syncthreads();
    #pragma unroll
    for (int off = 1; off < 256; off <<= 1) {
        int t = (tid >= off) ? sh[tid - off] : 0;
        __syncthreads();
        sh[tid] += t;
        __syncthreads();
    }
    spart[tid] = sh[tid] - v;   // exclusive
}

__global__ __launch_bounds__(256) void k_scan_add(const int* __restrict__ deg,
                                                  const int* __restrict__ spart,
                                                  int* __restrict__ rowptr,
                                                  int* __restrict__ cursor,
                                                  float* __restrict__ dinv) {
    int i = blockIdx.x * 256 + threadIdx.x;
    if (i < N_NODES) {
        int d = deg[i];
        int v = rowptr[i + 1] + spart[blockIdx.x];
        rowptr[i + 1] = v;
        cursor[i] = v - d;
        dinv[i] = rsqrtf((float)(d + 1));   // +1 self loop
    }
}

__global__ __launch_bounds__(256) void k_scatter(const int* __restrict__ src,
                                                 const int* __restrict__ dst,
                                                 int* __restrict__ cursor,
                                                 int* __restrict__ colsrc) {
    int e = blockIdx.x * 256 + threadIdx.x;   // grid exact
    int d = dst[e];
    int slot = atomicAdd(&cursor[d], 1);
    colsrc[slot] = src[e];
}

// ---------------- dense: out = X @ W   (NxD @ DxD) ----------------

__global__ __launch_bounds__(256) void k_gemm(const float* __restrict__ X,
                                              const float* __restrict__ W,
                                              float* __restrict__ out) {
    __shared__ float Wl[64][64];
    int tid = threadIdx.x;
    {   // stage W into LDS (16 KB)
        const float4* Wv = (const float4*)W;
        float4* Wlv = (float4*)&Wl[0][0];
        #pragma unroll
        for (int i = 0; i < 4; ++i) Wlv[tid + 256 * i] = Wv[tid + 256 * i];
    }
    __syncthreads();
    int r = blockIdx.x * 16 + (tid >> 4);
    int c0 = (tid & 15) << 2;
    const float4* xrow = (const float4*)(X + (size_t)r * D_FEAT);
    float ax = 0.f, ay = 0.f, az = 0.f, aw = 0.f;
    #pragma unroll
    for (int k4 = 0; k4 < 16; ++k4) {
        float4 xv = xrow[k4];
        #pragma unroll
        for (int j = 0; j < 4; ++j) {
            float xs = (j == 0) ? xv.x : (j == 1) ? xv.y : (j == 2) ? xv.z : xv.w;
            const float4 wv = *(const float4*)&Wl[4 * k4 + j][c0];
            ax += xs * wv.x; ay += xs * wv.y; az += xs * wv.z; aw += xs * wv.w;
        }
    }
    float4 res; res.x = ax; res.y = ay; res.z = az; res.w = aw;
    *(float4*)(out + (size_t)r * D_FEAT + c0) = res;
}

// ---------------- aggregation: one wave per node ----------------
// out[i][f] = relu( dinv_i * sum_{s in nbr(i)} hm[s][f]*dinv_s
//                   + hm[i][f]*dinv_i^2 + bias[f] )

__global__ __launch_bounds__(256) void k_agg_relu(const float* __restrict__ hm,
                                                  const int* __restrict__ rowptr,
                                                  const int* __restrict__ colsrc,
                                                  const float* __restrict__ dinv,
                                                  const float* __restrict__ bias,
                                                  float* __restrict__ outp) {
    int node = blockIdx.x * 4 + (threadIdx.x >> 6);   // grid exact: 12500*4
    int f = threadIdx.x & 63;
    int beg = rowptr[node];
    int end = rowptr[node + 1];
    float acc = 0.0f;
    for (int e = beg; e < end; ++e) {
        int s = colsrc[e];
        acc += hm[(size_t)s * D_FEAT + f] * dinv[s];
    }
    float di = dinv[node];
    float v = acc * di + hm[(size_t)node * D_FEAT + f] * (di * di) + bias[f];
    outp[(size_t)node * D_FEAT + f] = fmaxf(v, 0.0f);
}

// layer-2 aggregation fused with +b2, relu, dot(Wfc), block partial sum
__global__ __launch_bounds__(256) void k_agg2_dot(const float* __restrict__ hm,
                                                  const int* __restrict__ rowptr,
                                                  const int* __restrict__ colsrc,
                                                  const float* __restrict__ dinv,
                                                  const float* __restrict__ bias,
                                                  const float* __restrict__ Wfc,
                                                  float* __restrict__ partials) {
    __shared__ float red[4];
    int node = blockIdx.x * 4 + (threadIdx.x >> 6);
    int f = threadIdx.x & 63;
    int beg = rowptr[node];
    int end = rowptr[node + 1];
    float acc = 0.0f;
    for (int e = beg; e < end; ++e) {
        int s = colsrc[e];
        acc += hm[(size_t)s * D_FEAT + f] * dinv[s];
    }
    float di = dinv[node];
    float v = acc * di + hm[(size_t)node * D_FEAT + f] * (di * di) + bias[f];
    float contrib = fmaxf(v, 0.0f) * Wfc[f];
    #pragma unroll
    for (int off = 32; off > 0; off >>= 1) contrib += __shfl_down(contrib, off, 64);
    if ((threadIdx.x & 63) == 0) red[threadIdx.x >> 6] = contrib;
    __syncthreads();
    if (threadIdx.x == 0) partials[blockIdx.x] = red[0] + red[1] + red[2] + red[3];
}

__global__ __launch_bounds__(256) void k_final(const float* __restrict__ partials,
                                               const float* __restrict__ bfc,
                                               float* __restrict__ out) {
    __shared__ float red[4];
    float s = 0.0f;
    for (int i = threadIdx.x; i < AGG_BLOCKS; i += 256) s += partials[i];
    #pragma unroll
    for (int off = 32; off > 0; off >>= 1) s += __shfl_down(s, off, 64);
    if ((threadIdx.x & 63) == 0) red[threadIdx.x >> 6] = s;
    __syncthreads();
    if (threadIdx.x == 0) {
        float t = red[0] + red[1] + red[2] + red[3];
        float z = t / (float)N_NODES + bfc[0];
        out[0] = 1.0f / (1.0f + expf(-z));
    }
}

// ---------------- launcher ----------------

extern "C" void kernel_launch(void* const* d_in, const int* in_sizes, int n_in,
                              void* d_out, int out_size, void* d_ws, size_t ws_size,
                              hipStream_t stream) {
    const float* x   = (const float*)d_in[0];
    const int*   ei  = (const int*)d_in[1];
    const int*   src = ei;               // edge_index[0]
    const int*   dst = ei + N_EDGES;     // edge_index[1]
    const float* W1  = (const float*)d_in[2];
    const float* b1  = (const float*)d_in[3];
    const float* W2  = (const float*)d_in[4];
    const float* b2  = (const float*)d_in[5];
    const float* Wfc = (const float*)d_in[6];
    const float* bfc = (const float*)d_in[7];
    float* out = (float*)d_out;

    char* ws = (char*)d_ws;
    size_t off = 0;
    auto alloc = [&](size_t bytes) -> char* {
        char* p = ws + off;
        off += (bytes + 255) & ~(size_t)255;
        return p;
    };
    int*   deg      = (int*)alloc((size_t)N_NODES * 4);
    float* dinv     = (float*)alloc((size_t)N_NODES * 4);
    int*   rowptr   = (int*)alloc((size_t)(N_NODES + 1) * 4);
    int*   cursor   = (int*)alloc((size_t)N_NODES * 4);
    int*   spart    = (int*)alloc(256 * 4);
    int*   colsrc   = (int*)alloc((size_t)N_EDGES * 4);
    float* partials = (float*)alloc((size_t)AGG_BLOCKS * 4);
    float* bufA     = (float*)alloc((size_t)N_NODES * D_FEAT * 4);
    float* bufB     = (float*)alloc((size_t)N_NODES * D_FEAT * 4);

    // CSR build (by dst)
    k_init     <<<SCAN_BLOCKS, 256, 0, stream>>>(deg);
    k_hist     <<<EDGE_BLOCKS, 256, 0, stream>>>(dst, deg);
    k_scan_part<<<SCAN_BLOCKS, 256, 0, stream>>>(deg, rowptr, spart);
    k_scan_tops<<<1,           256, 0, stream>>>(spart);
    k_scan_add <<<SCAN_BLOCKS, 256, 0, stream>>>(deg, spart, rowptr, cursor, dinv);
    k_scatter  <<<EDGE_BLOCKS, 256, 0, stream>>>(src, dst, cursor, colsrc);

    // layer 1: hm = x@W1 ; h1 = relu(agg(hm) + b1)
    k_gemm     <<<GEMM_BLOCKS, 256, 0, stream>>>(x, W1, bufA);
    k_agg_relu <<<AGG_BLOCKS,  256, 0, stream>>>(bufA, rowptr, colsrc, dinv, b1, bufB);

    // layer 2: hm2 = h1@W2 ; fused agg + b2 + relu + dot(Wfc) + partial mean
    k_gemm     <<<GEMM_BLOCKS, 256, 0, stream>>>(bufB, W2, bufA);
    k_agg2_dot <<<AGG_BLOCKS,  256, 0, stream>>>(bufA, rowptr, colsrc, dinv, b2, Wfc, partials);

    // final: sigmoid(mean + bfc)
    k_final    <<<1, 256, 0, stream>>>(partials, bfc, out);
}

// Round 4
// 210.836 us; speedup vs baseline: 1.4477x; 1.4477x over previous
//
// GCN2 on MI355X — CSR gather aggregation with lane-batched indices + 8-way MLP unroll (r3).
#include <hip/hip_runtime.h>
#include <math.h>

#define N_NODES 50000
#define N_EDGES 800000
#define D_FEAT 64

#define SCAN_CHUNK 256
#define SCAN_BLOCKS ((N_NODES + SCAN_CHUNK - 1) / SCAN_CHUNK)   // 196
#define AGG_BLOCKS (N_NODES / 4)                                 // 12500 (exact)
#define GEMM_BLOCKS (N_NODES / 16)                               // 3125 (exact)
#define EDGE_BLOCKS (N_EDGES / 256)                              // 3125 (exact)

// ---------------- CSR build ----------------

__global__ __launch_bounds__(256) void k_init(int* __restrict__ deg) {
    int i = blockIdx.x * 256 + threadIdx.x;
    if (i < N_NODES) deg[i] = 0;
}

__global__ __launch_bounds__(256) void k_hist(const int* __restrict__ dst,
                                              int* __restrict__ deg) {
    int e = blockIdx.x * 256 + threadIdx.x;   // grid exact
    atomicAdd(&deg[dst[e]], 1);
}

__global__ __launch_bounds__(256) void k_scan_part(const int* __restrict__ deg,
                                                   int* __restrict__ rowptr,
                                                   int* __restrict__ spart) {
    __shared__ int sh[256];
    int tid = threadIdx.x;
    int i = blockIdx.x * 256 + tid;
    int v = (i < N_NODES) ? deg[i] : 0;
    sh[tid] = v;
    __syncthreads();
    #pragma unroll
    for (int off = 1; off < 256; off <<= 1) {
        int t = (tid >= off) ? sh[tid - off] : 0;
        __syncthreads();
        sh[tid] += t;
        __syncthreads();
    }
    if (i < N_NODES) rowptr[i + 1] = sh[tid];
    if (tid == 255) spart[blockIdx.x] = sh[255];
    if (i == 0) rowptr[0] = 0;
}

__global__ __launch_bounds__(256) void k_scan_tops(int* __restrict__ spart) {
    __shared__ int sh[256];
    int tid = threadIdx.x;
    int v = (tid < SCAN_BLOCKS) ? spart[tid] : 0;
    sh[tid] = v;
    __syncthreads();
    #pragma unroll
    for (int off = 1; off < 256; off <<= 1) {
        int t = (tid >= off) ? sh[tid - off] : 0;
        __syncthreads();
        sh[tid] += t;
        __syncthreads();
    }
    spart[tid] = sh[tid] - v;   // exclusive
}

__global__ __launch_bounds__(256) void k_scan_add(const int* __restrict__ deg,
                                                  const int* __restrict__ spart,
                                                  int* __restrict__ rowptr,
                                                  int* __restrict__ cursor,
                                                  float* __restrict__ dinv) {
    int i = blockIdx.x * 256 + threadIdx.x;
    if (i < N_NODES) {
        int d = deg[i];
        int v = rowptr[i + 1] + spart[blockIdx.x];
        rowptr[i + 1] = v;
        cursor[i] = v - d;
        dinv[i] = rsqrtf((float)(d + 1));   // +1 self loop
    }
}

__global__ __launch_bounds__(256) void k_scatter(const int* __restrict__ src,
                                                 const int* __restrict__ dst,
                                                 int* __restrict__ cursor,
                                                 int* __restrict__ colsrc) {
    int e = blockIdx.x * 256 + threadIdx.x;   // grid exact
    int d = dst[e];
    int slot = atomicAdd(&cursor[d], 1);
    colsrc[slot] = src[e];
}

// ---------------- dense: out = X @ W   (NxD @ DxD) ----------------

__global__ __launch_bounds__(256) void k_gemm(const float* __restrict__ X,
                                              const float* __restrict__ W,
                                              float* __restrict__ out) {
    __shared__ float Wl[64][64];
    int tid = threadIdx.x;
    {   // stage W into LDS (16 KB)
        const float4* Wv = (const float4*)W;
        float4* Wlv = (float4*)&Wl[0][0];
        #pragma unroll
        for (int i = 0; i < 4; ++i) Wlv[tid + 256 * i] = Wv[tid + 256 * i];
    }
    __syncthreads();
    int r = blockIdx.x * 16 + (tid >> 4);
    int c0 = (tid & 15) << 2;
    const float4* xrow = (const float4*)(X + (size_t)r * D_FEAT);
    float ax = 0.f, ay = 0.f, az = 0.f, aw = 0.f;
    #pragma unroll
    for (int k4 = 0; k4 < 16; ++k4) {
        float4 xv = xrow[k4];
        #pragma unroll
        for (int j = 0; j < 4; ++j) {
            float xs = (j == 0) ? xv.x : (j == 1) ? xv.y : (j == 2) ? xv.z : xv.w;
            const float4 wv = *(const float4*)&Wl[4 * k4 + j][c0];
            ax += xs * wv.x; ay += xs * wv.y; az += xs * wv.z; aw += xs * wv.w;
        }
    }
    float4 res; res.x = ax; res.y = ay; res.z = az; res.w = aw;
    *(float4*)(out + (size_t)r * D_FEAT + c0) = res;
}

// ---------------- aggregation gather core ----------------
// One wave per node. Lane f owns feature f. Indices loaded coalesced by the
// wave (lane l -> colsrc[beg+l]), broadcast via shfl, then hm-row gathers
// issued 8-wide (independent) for memory-level parallelism.

__device__ __forceinline__ float agg_gather(const float* __restrict__ hm,
                                            const int* __restrict__ colsrc,
                                            const float* __restrict__ dinv,
                                            int beg, int deg, int f) {
    float acc = 0.0f;
    for (int base = 0; base < deg; base += 64) {
        int cnt = deg - base; if (cnt > 64) cnt = 64;
        int idx = 0; float w = 0.0f;
        if (f < cnt) { idx = colsrc[beg + base + f]; w = dinv[idx]; }
        int j = 0;
        for (; j + 8 <= cnt; j += 8) {
            int   sj[8];
            float wj[8], vj[8];
            #pragma unroll
            for (int u = 0; u < 8; ++u) {
                sj[u] = __shfl(idx, j + u, 64);
                wj[u] = __shfl(w,   j + u, 64);
            }
            #pragma unroll
            for (int u = 0; u < 8; ++u) vj[u] = hm[(size_t)sj[u] * D_FEAT + f];
            #pragma unroll
            for (int u = 0; u < 8; ++u) acc += vj[u] * wj[u];
        }
        for (; j < cnt; ++j) {
            int   s  = __shfl(idx, j, 64);
            float ws = __shfl(w,   j, 64);
            acc += hm[(size_t)s * D_FEAT + f] * ws;
        }
    }
    return acc;
}

// out[i][f] = relu( dinv_i * sum_{s in nbr(i)} hm[s][f]*dinv_s
//                   + hm[i][f]*dinv_i^2 + bias[f] )
__global__ __launch_bounds__(256) void k_agg_relu(const float* __restrict__ hm,
                                                  const int* __restrict__ rowptr,
                                                  const int* __restrict__ colsrc,
                                                  const float* __restrict__ dinv,
                                                  const float* __restrict__ bias,
                                                  float* __restrict__ outp) {
    int node = blockIdx.x * 4 + (threadIdx.x >> 6);   // grid exact: 12500*4
    int f = threadIdx.x & 63;
    int beg = rowptr[node];
    int end = rowptr[node + 1];
    float self = hm[(size_t)node * D_FEAT + f];       // issue self-row early
    float acc = agg_gather(hm, colsrc, dinv, beg, end - beg, f);
    float di = dinv[node];
    float v = acc * di + self * (di * di) + bias[f];
    outp[(size_t)node * D_FEAT + f] = fmaxf(v, 0.0f);
}

// layer-2 aggregation fused with +b2, relu, dot(Wfc), block partial sum
__global__ __launch_bounds__(256) void k_agg2_dot(const float* __restrict__ hm,
                                                  const int* __restrict__ rowptr,
                                                  const int* __restrict__ colsrc,
                                                  const float* __restrict__ dinv,
                                                  const float* __restrict__ bias,
                                                  const float* __restrict__ Wfc,
                                                  float* __restrict__ partials) {
    __shared__ float red[4];
    int node = blockIdx.x * 4 + (threadIdx.x >> 6);
    int f = threadIdx.x & 63;
    int beg = rowptr[node];
    int end = rowptr[node + 1];
    float self = hm[(size_t)node * D_FEAT + f];
    float acc = agg_gather(hm, colsrc, dinv, beg, end - beg, f);
    float di = dinv[node];
    float v = acc * di + self * (di * di) + bias[f];
    float contrib = fmaxf(v, 0.0f) * Wfc[f];
    #pragma unroll
    for (int off = 32; off > 0; off >>= 1) contrib += __shfl_down(contrib, off, 64);
    if ((threadIdx.x & 63) == 0) red[threadIdx.x >> 6] = contrib;
    __syncthreads();
    if (threadIdx.x == 0) partials[blockIdx.x] = red[0] + red[1] + red[2] + red[3];
}

__global__ __launch_bounds__(256) void k_final(const float* __restrict__ partials,
                                               const float* __restrict__ bfc,
                                               float* __restrict__ out) {
    __shared__ float red[4];
    float s = 0.0f;
    for (int i = threadIdx.x; i < AGG_BLOCKS; i += 256) s += partials[i];
    #pragma unroll
    for (int off = 32; off > 0; off >>= 1) s += __shfl_down(s, off, 64);
    if ((threadIdx.x & 63) == 0) red[threadIdx.x >> 6] = s;
    __syncthreads();
    if (threadIdx.x == 0) {
        float t = red[0] + red[1] + red[2] + red[3];
        float z = t / (float)N_NODES + bfc[0];
        out[0] = 1.0f / (1.0f + expf(-z));
    }
}

// ---------------- launcher ----------------

extern "C" void kernel_launch(void* const* d_in, const int* in_sizes, int n_in,
                              void* d_out, int out_size, void* d_ws, size_t ws_size,
                              hipStream_t stream) {
    const float* x   = (const float*)d_in[0];
    const int*   ei  = (const int*)d_in[1];
    const int*   src = ei;               // edge_index[0]
    const int*   dst = ei + N_EDGES;     // edge_index[1]
    const float* W1  = (const float*)d_in[2];
    const float* b1  = (const float*)d_in[3];
    const float* W2  = (const float*)d_in[4];
    const float* b2  = (const float*)d_in[5];
    const float* Wfc = (const float*)d_in[6];
    const float* bfc = (const float*)d_in[7];
    float* out = (float*)d_out;

    char* ws = (char*)d_ws;
    size_t off = 0;
    auto alloc = [&](size_t bytes) -> char* {
        char* p = ws + off;
        off += (bytes + 255) & ~(size_t)255;
        return p;
    };
    int*   deg      = (int*)alloc((size_t)N_NODES * 4);
    float* dinv     = (float*)alloc((size_t)N_NODES * 4);
    int*   rowptr   = (int*)alloc((size_t)(N_NODES + 1) * 4);
    int*   cursor   = (int*)alloc((size_t)N_NODES * 4);
    int*   spart    = (int*)alloc(256 * 4);
    int*   colsrc   = (int*)alloc((size_t)N_EDGES * 4);
    float* partials = (float*)alloc((size_t)AGG_BLOCKS * 4);
    float* bufA     = (float*)alloc((size_t)N_NODES * D_FEAT * 4);
    float* bufB     = (float*)alloc((size_t)N_NODES * D_FEAT * 4);

    // CSR build (by dst)
    k_init     <<<SCAN_BLOCKS, 256, 0, stream>>>(deg);
    k_hist     <<<EDGE_BLOCKS, 256, 0, stream>>>(dst, deg);
    k_scan_part<<<SCAN_BLOCKS, 256, 0, stream>>>(deg, rowptr, spart);
    k_scan_tops<<<1,           256, 0, stream>>>(spart);
    k_scan_add <<<SCAN_BLOCKS, 256, 0, stream>>>(deg, spart, rowptr, cursor, dinv);
    k_scatter  <<<EDGE_BLOCKS, 256, 0, stream>>>(src, dst, cursor, colsrc);

    // layer 1: hm = x@W1 ; h1 = relu(agg(hm) + b1)
    k_gemm     <<<GEMM_BLOCKS, 256, 0, stream>>>(x, W1, bufA);
    k_agg_relu <<<AGG_BLOCKS,  256, 0, stream>>>(bufA, rowptr, colsrc, dinv, b1, bufB);

    // layer 2: hm2 = h1@W2 ; fused agg + b2 + relu + dot(Wfc) + partial mean
    k_gemm     <<<GEMM_BLOCKS, 256, 0, stream>>>(bufB, W2, bufA);
    k_agg2_dot <<<AGG_BLOCKS,  256, 0, stream>>>(bufA, rowptr, colsrc, dinv, b2, Wfc, partials);

    // final: sigmoid(mean + bfc)
    k_final    <<<1, 256, 0, stream>>>(partials, bfc, out);
}

// Round 5
// 147.489 us; speedup vs baseline: 2.0695x; 1.4295x over previous
//
// GCN2 on MI355X — r4: bucket-partitioned CSR build (coalesced writes), LDS exact-grouping.
// Agg kernels unchanged from r3 (lane-batched indices + 8-way MLP gather).
#include <hip/hip_runtime.h>
#include <math.h>

#define N_NODES 50000
#define N_EDGES 800000
#define D_FEAT 64

#define NBUCKET 196            // dst>>8, max 49999>>8 = 195
#define P1_BLOCKS 196          // 196*4096 = 802816 >= E
#define P1_EPB 4096            // edges per p1 block
#define BCAP 6144              // per-bucket edge capacity (mean 4096, sigma 64)

#define SCAN_N (NBUCKET * P1_BLOCKS)            // 38416
#define SCAN_NB ((SCAN_N + 255) / 256)          // 151

#define AGG_BLOCKS (N_NODES / 4)                // 12500 (exact)
#define GEMM_BLOCKS (N_NODES / 16)              // 3125 (exact)

// ---------------- pass 1: coarse bucket partition ----------------

__global__ __launch_bounds__(256) void k_p1hist(const int* __restrict__ dst,
                                                int* __restrict__ cnt) {
    __shared__ int h[NBUCKET];
    int tid = threadIdx.x;
    for (int i = tid; i < NBUCKET; i += 256) h[i] = 0;
    __syncthreads();
    int e0 = blockIdx.x * P1_EPB;
    #pragma unroll
    for (int k = 0; k < P1_EPB / 256; ++k) {
        int e = e0 + k * 256 + tid;
        if (e < N_EDGES) atomicAdd(&h[dst[e] >> 8], 1);
    }
    __syncthreads();
    for (int i = tid; i < NBUCKET; i += 256)
        cnt[i * P1_BLOCKS + blockIdx.x] = h[i];   // bucket-major
}

// generic 3-kernel exclusive scan over SCAN_N ints
__global__ __launch_bounds__(256) void k_sc_part(const int* __restrict__ in,
                                                 int* __restrict__ outx,
                                                 int* __restrict__ spart) {
    __shared__ int sh[256];
    int tid = threadIdx.x;
    int i = blockIdx.x * 256 + tid;
    int v = (i < SCAN_N) ? in[i] : 0;
    sh[tid] = v;
    __syncthreads();
    #pragma unroll
    for (int off = 1; off < 256; off <<= 1) {
        int t = (tid >= off) ? sh[tid - off] : 0;
        __syncthreads();
        sh[tid] += t;
        __syncthreads();
    }
    if (i < SCAN_N) outx[i] = sh[tid] - v;        // exclusive within block
    if (tid == 255) spart[blockIdx.x] = sh[255];
}

__global__ __launch_bounds__(256) void k_sc_tops(int* __restrict__ spart) {
    __shared__ int sh[256];
    int tid = threadIdx.x;
    int v = (tid < SCAN_NB) ? spart[tid] : 0;
    sh[tid] = v;
    __syncthreads();
    #pragma unroll
    for (int off = 1; off < 256; off <<= 1) {
        int t = (tid >= off) ? sh[tid - off] : 0;
        __syncthreads();
        sh[tid] += t;
        __syncthreads();
    }
    spart[tid] = sh[tid] - v;                     // exclusive
}

__global__ __launch_bounds__(256) void k_sc_add(int* __restrict__ outx,
                                                const int* __restrict__ spart) {
    int i = blockIdx.x * 256 + threadIdx.x;
    if (i < SCAN_N) outx[i] += spart[blockIdx.x];
}

__global__ __launch_bounds__(256) void k_p1scatter(const int* __restrict__ src,
                                                   const int* __restrict__ dst,
                                                   const int* __restrict__ base,
                                                   unsigned* __restrict__ ebuf) {
    __shared__ int h[NBUCKET];                    // running cursor per bucket
    int tid = threadIdx.x;
    for (int i = tid; i < NBUCKET; i += 256)
        h[i] = base[i * P1_BLOCKS + blockIdx.x];
    __syncthreads();
    int e0 = blockIdx.x * P1_EPB;
    #pragma unroll
    for (int k = 0; k < P1_EPB / 256; ++k) {
        int e = e0 + k * 256 + tid;
        if (e < N_EDGES) {
            int d = dst[e];
            int slot = atomicAdd(&h[d >> 8], 1);
            ebuf[slot] = (unsigned)src[e] | ((unsigned)(d & 255) << 16);
        }
    }
}

// ---------------- pass 2: exact grouping in LDS; emits colsrc/rowptr/dinv ----------------

__global__ __launch_bounds__(256) void k_p2group(const unsigned* __restrict__ ebuf,
                                                 const int* __restrict__ base,
                                                 int* __restrict__ rowptr,
                                                 int* __restrict__ colsrc,
                                                 float* __restrict__ dinv) {
    __shared__ unsigned eloc[BCAP];
    __shared__ int hist[256];
    __shared__ int sh[256];
    int tid = threadIdx.x;
    int b = blockIdx.x;
    int start = base[b * P1_BLOCKS];
    int end = (b == NBUCKET - 1) ? N_EDGES : base[(b + 1) * P1_BLOCKS];
    int cnt = end - start;
    hist[tid] = 0;
    __syncthreads();
    for (int i = tid; i < cnt; i += 256) {
        unsigned p = ebuf[start + i];
        eloc[i] = p;
        atomicAdd(&hist[(p >> 16) & 255], 1);
    }
    __syncthreads();
    int v = hist[tid];                            // degree of node b*256+tid
    sh[tid] = v;
    __syncthreads();
    #pragma unroll
    for (int off = 1; off < 256; off <<= 1) {
        int t = (tid >= off) ? sh[tid - off] : 0;
        __syncthreads();
        sh[tid] += t;
        __syncthreads();
    }
    int binoff = sh[tid] - v;                     // exclusive
    int node = b * 256 + tid;                     // up to 50175; arrays sized for it
    rowptr[node] = start + binoff;
    dinv[node] = rsqrtf((float)(v + 1));          // +1 self loop
    hist[tid] = start + binoff;                   // reuse as cursor
    __syncthreads();
    for (int i = tid; i < cnt; i += 256) {
        unsigned p = eloc[i];
        int slot = atomicAdd(&hist[(p >> 16) & 255], 1);
        colsrc[slot] = (int)(p & 0xFFFFu);
    }
}

// ---------------- dense: out = X @ W   (NxD @ DxD) ----------------

__global__ __launch_bounds__(256) void k_gemm(const float* __restrict__ X,
                                              const float* __restrict__ W,
                                              float* __restrict__ out) {
    __shared__ float Wl[64][64];
    int tid = threadIdx.x;
    {
        const float4* Wv = (const float4*)W;
        float4* Wlv = (float4*)&Wl[0][0];
        #pragma unroll
        for (int i = 0; i < 4; ++i) Wlv[tid + 256 * i] = Wv[tid + 256 * i];
    }
    __syncthreads();
    int r = blockIdx.x * 16 + (tid >> 4);
    int c0 = (tid & 15) << 2;
    const float4* xrow = (const float4*)(X + (size_t)r * D_FEAT);
    float ax = 0.f, ay = 0.f, az = 0.f, aw = 0.f;
    #pragma unroll
    for (int k4 = 0; k4 < 16; ++k4) {
        float4 xv = xrow[k4];
        #pragma unroll
        for (int j = 0; j < 4; ++j) {
            float xs = (j == 0) ? xv.x : (j == 1) ? xv.y : (j == 2) ? xv.z : xv.w;
            const float4 wv = *(const float4*)&Wl[4 * k4 + j][c0];
            ax += xs * wv.x; ay += xs * wv.y; az += xs * wv.z; aw += xs * wv.w;
        }
    }
    float4 res; res.x = ax; res.y = ay; res.z = az; res.w = aw;
    *(float4*)(out + (size_t)r * D_FEAT + c0) = res;
}

// ---------------- aggregation (unchanged from r3) ----------------

__device__ __forceinline__ float agg_gather(const float* __restrict__ hm,
                                            const int* __restrict__ colsrc,
                                            const float* __restrict__ dinv,
                                            int beg, int deg, int f) {
    float acc = 0.0f;
    for (int base = 0; base < deg; base += 64) {
        int cnt = deg - base; if (cnt > 64) cnt = 64;
        int idx = 0; float w = 0.0f;
        if (f < cnt) { idx = colsrc[beg + base + f]; w = dinv[idx]; }
        int j = 0;
        for (; j + 8 <= cnt; j += 8) {
            int   sj[8];
            float wj[8], vj[8];
            #pragma unroll
            for (int u = 0; u < 8; ++u) {
                sj[u] = __shfl(idx, j + u, 64);
                wj[u] = __shfl(w,   j + u, 64);
            }
            #pragma unroll
            for (int u = 0; u < 8; ++u) vj[u] = hm[(size_t)sj[u] * D_FEAT + f];
            #pragma unroll
            for (int u = 0; u < 8; ++u) acc += vj[u] * wj[u];
        }
        for (; j < cnt; ++j) {
            int   s  = __shfl(idx, j, 64);
            float ws = __shfl(w,   j, 64);
            acc += hm[(size_t)s * D_FEAT + f] * ws;
        }
    }
    return acc;
}

__global__ __launch_bounds__(256) void k_agg_relu(const float* __restrict__ hm,
                                                  const int* __restrict__ rowptr,
                                                  const int* __restrict__ colsrc,
                                                  const float* __restrict__ dinv,
                                                  const float* __restrict__ bias,
                                                  float* __restrict__ outp) {
    int node = blockIdx.x * 4 + (threadIdx.x >> 6);
    int f = threadIdx.x & 63;
    int beg = rowptr[node];
    int end = rowptr[node + 1];
    float self = hm[(size_t)node * D_FEAT + f];
    float acc = agg_gather(hm, colsrc, dinv, beg, end - beg, f);
    float di = dinv[node];
    float v = acc * di + self * (di * di) + bias[f];
    outp[(size_t)node * D_FEAT + f] = fmaxf(v, 0.0f);
}

__global__ __launch_bounds__(256) void k_agg2_dot(const float* __restrict__ hm,
                                                  const int* __restrict__ rowptr,
                                                  const int* __restrict__ colsrc,
                                                  const float* __restrict__ dinv,
                                                  const float* __restrict__ bias,
                                                  const float* __restrict__ Wfc,
                                                  float* __restrict__ partials) {
    __shared__ float red[4];
    int node = blockIdx.x * 4 + (threadIdx.x >> 6);
    int f = threadIdx.x & 63;
    int beg = rowptr[node];
    int end = rowptr[node + 1];
    float self = hm[(size_t)node * D_FEAT + f];
    float acc = agg_gather(hm, colsrc, dinv, beg, end - beg, f);
    float di = dinv[node];
    float v = acc * di + self * (di * di) + bias[f];
    float contrib = fmaxf(v, 0.0f) * Wfc[f];
    #pragma unroll
    for (int off = 32; off > 0; off >>= 1) contrib += __shfl_down(contrib, off, 64);
    if ((threadIdx.x & 63) == 0) red[threadIdx.x >> 6] = contrib;
    __syncthreads();
    if (threadIdx.x == 0) partials[blockIdx.x] = red[0] + red[1] + red[2] + red[3];
}

__global__ __launch_bounds__(256) void k_final(const float* __restrict__ partials,
                                               const float* __restrict__ bfc,
                                               float* __restrict__ out) {
    __shared__ float red[4];
    float s = 0.0f;
    for (int i = threadIdx.x; i < AGG_BLOCKS; i += 256) s += partials[i];
    #pragma unroll
    for (int off = 32; off > 0; off >>= 1) s += __shfl_down(s, off, 64);
    if ((threadIdx.x & 63) == 0) red[threadIdx.x >> 6] = s;
    __syncthreads();
    if (threadIdx.x == 0) {
        float t = red[0] + red[1] + red[2] + red[3];
        float z = t / (float)N_NODES + bfc[0];
        out[0] = 1.0f / (1.0f + expf(-z));
    }
}

// ---------------- launcher ----------------

extern "C" void kernel_launch(void* const* d_in, const int* in_sizes, int n_in,
                              void* d_out, int out_size, void* d_ws, size_t ws_size,
                              hipStream_t stream) {
    const float* x   = (const float*)d_in[0];
    const int*   ei  = (const int*)d_in[1];
    const int*   src = ei;               // edge_index[0]
    const int*   dst = ei + N_EDGES;     // edge_index[1]
    const float* W1  = (const float*)d_in[2];
    const float* b1  = (const float*)d_in[3];
    const float* W2  = (const float*)d_in[4];
    const float* b2  = (const float*)d_in[5];
    const float* Wfc = (const float*)d_in[6];
    const float* bfc = (const float*)d_in[7];
    float* out = (float*)d_out;

    char* ws = (char*)d_ws;
    size_t off = 0;
    auto alloc = [&](size_t bytes) -> char* {
        char* p = ws + off;
        off += (bytes + 255) & ~(size_t)255;
        return p;
    };
    int*      cnt      = (int*)alloc((size_t)SCAN_N * 4);
    int*      basex    = (int*)alloc((size_t)SCAN_N * 4);
    int*      spart    = (int*)alloc(256 * 4);
    unsigned* ebuf     = (unsigned*)alloc((size_t)N_EDGES * 4);
    int*      colsrc   = (int*)alloc((size_t)N_EDGES * 4);
    int*      rowptr   = (int*)alloc((size_t)(NBUCKET * 256 + 1) * 4);   // 50177
    float*    dinv     = (float*)alloc((size_t)(NBUCKET * 256) * 4);     // 50176
    float*    partials = (float*)alloc((size_t)AGG_BLOCKS * 4);
    float*    bufA     = (float*)alloc((size_t)N_NODES * D_FEAT * 4);
    float*    bufB     = (float*)alloc((size_t)N_NODES * D_FEAT * 4);

    // CSR build: coarse partition -> exact LDS grouping
    k_p1hist   <<<P1_BLOCKS, 256, 0, stream>>>(dst, cnt);
    k_sc_part  <<<SCAN_NB,   256, 0, stream>>>(cnt, basex, spart);
    k_sc_tops  <<<1,         256, 0, stream>>>(spart);
    k_sc_add   <<<SCAN_NB,   256, 0, stream>>>(basex, spart);
    k_p1scatter<<<P1_BLOCKS, 256, 0, stream>>>(src, dst, basex, ebuf);
    k_p2group  <<<NBUCKET,   256, 0, stream>>>(ebuf, basex, rowptr, colsrc, dinv);

    // layer 1: hm = x@W1 ; h1 = relu(agg(hm) + b1)
    k_gemm     <<<GEMM_BLOCKS, 256, 0, stream>>>(x, W1, bufA);
    k_agg_relu <<<AGG_BLOCKS,  256, 0, stream>>>(bufA, rowptr, colsrc, dinv, b1, bufB);

    // layer 2: hm2 = h1@W2 ; fused agg + b2 + relu + dot(Wfc) + partial mean
    k_gemm     <<<GEMM_BLOCKS, 256, 0, stream>>>(bufB, W2, bufA);
    k_agg2_dot <<<AGG_BLOCKS,  256, 0, stream>>>(bufA, rowptr, colsrc, dinv, b2, Wfc, partials);

    // final: sigmoid(mean + bfc)
    k_final    <<<1, 256, 0, stream>>>(partials, bfc, out);
}

// Round 6
// 139.130 us; speedup vs baseline: 2.1939x; 1.0601x over previous
//
// GCN2 on MI355X — r5: fp16 feature storage for gather-bandwidth halving (f32 accumulate).
// CSR build via bucket partition (r4); agg with lane-batched indices + 8-way MLP (r3).
#include <hip/hip_runtime.h>
#include <hip/hip_fp16.h>
#include <math.h>

#define N_NODES 50000
#define N_EDGES 800000
#define D_FEAT 64

#define NBUCKET 196            // dst>>8, max 49999>>8 = 195
#define P1_BLOCKS 196          // 196*4096 = 802816 >= E
#define P1_EPB 4096            // edges per p1 block
#define BCAP 6144              // per-bucket edge capacity (mean 4096, sigma 64)

#define SCAN_N (NBUCKET * P1_BLOCKS)            // 38416
#define SCAN_NB ((SCAN_N + 255) / 256)          // 151

#define AGG_BLOCKS (N_NODES / 4)                // 12500 (exact)
#define GEMM_BLOCKS (N_NODES / 16)              // 3125 (exact)

// ---------------- pass 1: coarse bucket partition ----------------

__global__ __launch_bounds__(256) void k_p1hist(const int* __restrict__ dst,
                                                int* __restrict__ cnt) {
    __shared__ int h[NBUCKET];
    int tid = threadIdx.x;
    for (int i = tid; i < NBUCKET; i += 256) h[i] = 0;
    __syncthreads();
    int e0 = blockIdx.x * P1_EPB;
    #pragma unroll
    for (int k = 0; k < P1_EPB / 256; ++k) {
        int e = e0 + k * 256 + tid;
        if (e < N_EDGES) atomicAdd(&h[dst[e] >> 8], 1);
    }
    __syncthreads();
    for (int i = tid; i < NBUCKET; i += 256)
        cnt[i * P1_BLOCKS + blockIdx.x] = h[i];   // bucket-major
}

// generic 3-kernel exclusive scan over SCAN_N ints
__global__ __launch_bounds__(256) void k_sc_part(const int* __restrict__ in,
                                                 int* __restrict__ outx,
                                                 int* __restrict__ spart) {
    __shared__ int sh[256];
    int tid = threadIdx.x;
    int i = blockIdx.x * 256 + tid;
    int v = (i < SCAN_N) ? in[i] : 0;
    sh[tid] = v;
    __syncthreads();
    #pragma unroll
    for (int off = 1; off < 256; off <<= 1) {
        int t = (tid >= off) ? sh[tid - off] : 0;
        __syncthreads();
        sh[tid] += t;
        __syncthreads();
    }
    if (i < SCAN_N) outx[i] = sh[tid] - v;        // exclusive within block
    if (tid == 255) spart[blockIdx.x] = sh[255];
}

__global__ __launch_bounds__(256) void k_sc_tops(int* __restrict__ spart) {
    __shared__ int sh[256];
    int tid = threadIdx.x;
    int v = (tid < SCAN_NB) ? spart[tid] : 0;
    sh[tid] = v;
    __syncthreads();
    #pragma unroll
    for (int off = 1; off < 256; off <<= 1) {
        int t = (tid >= off) ? sh[tid - off] : 0;
        __syncthreads();
        sh[tid] += t;
        __syncthreads();
    }
    spart[tid] = sh[tid] - v;                     // exclusive
}

__global__ __launch_bounds__(256) void k_sc_add(int* __restrict__ outx,
                                                const int* __restrict__ spart) {
    int i = blockIdx.x * 256 + threadIdx.x;
    if (i < SCAN_N) outx[i] += spart[blockIdx.x];
}

__global__ __launch_bounds__(256) void k_p1scatter(const int* __restrict__ src,
                                                   const int* __restrict__ dst,
                                                   const int* __restrict__ base,
                                                   unsigned* __restrict__ ebuf) {
    __shared__ int h[NBUCKET];                    // running cursor per bucket
    int tid = threadIdx.x;
    for (int i = tid; i < NBUCKET; i += 256)
        h[i] = base[i * P1_BLOCKS + blockIdx.x];
    __syncthreads();
    int e0 = blockIdx.x * P1_EPB;
    #pragma unroll
    for (int k = 0; k < P1_EPB / 256; ++k) {
        int e = e0 + k * 256 + tid;
        if (e < N_EDGES) {
            int d = dst[e];
            int slot = atomicAdd(&h[d >> 8], 1);
            ebuf[slot] = (unsigned)src[e] | ((unsigned)(d & 255) << 16);
        }
    }
}

// ---------------- pass 2: exact grouping in LDS; emits colsrc/rowptr/dinv ----------------

__global__ __launch_bounds__(256) void k_p2group(const unsigned* __restrict__ ebuf,
                                                 const int* __restrict__ base,
                                                 int* __restrict__ rowptr,
                                                 int* __restrict__ colsrc,
                                                 float* __restrict__ dinv) {
    __shared__ unsigned eloc[BCAP];
    __shared__ int hist[256];
    __shared__ int sh[256];
    int tid = threadIdx.x;
    int b = blockIdx.x;
    int start = base[b * P1_BLOCKS];
    int end = (b == NBUCKET - 1) ? N_EDGES : base[(b + 1) * P1_BLOCKS];
    int cnt = end - start;
    hist[tid] = 0;
    __syncthreads();
    for (int i = tid; i < cnt; i += 256) {
        unsigned p = ebuf[start + i];
        eloc[i] = p;
        atomicAdd(&hist[(p >> 16) & 255], 1);
    }
    __syncthreads();
    int v = hist[tid];                            // degree of node b*256+tid
    sh[tid] = v;
    __syncthreads();
    #pragma unroll
    for (int off = 1; off < 256; off <<= 1) {
        int t = (tid >= off) ? sh[tid - off] : 0;
        __syncthreads();
        sh[tid] += t;
        __syncthreads();
    }
    int binoff = sh[tid] - v;                     // exclusive
    int node = b * 256 + tid;                     // up to 50175; arrays sized for it
    rowptr[node] = start + binoff;
    dinv[node] = rsqrtf((float)(v + 1));          // +1 self loop
    hist[tid] = start + binoff;                   // reuse as cursor
    __syncthreads();
    for (int i = tid; i < cnt; i += 256) {
        unsigned p = eloc[i];
        int slot = atomicAdd(&hist[(p >> 16) & 255], 1);
        colsrc[slot] = (int)(p & 0xFFFFu);
    }
}

// ---------------- dense GEMMs: out(fp16) = X @ W ----------------

// layer 1: f32 input
__global__ __launch_bounds__(256) void k_gemm_f32(const float* __restrict__ X,
                                                  const float* __restrict__ W,
                                                  __half* __restrict__ out) {
    __shared__ float Wl[64][64];
    int tid = threadIdx.x;
    {
        const float4* Wv = (const float4*)W;
        float4* Wlv = (float4*)&Wl[0][0];
        #pragma unroll
        for (int i = 0; i < 4; ++i) Wlv[tid + 256 * i] = Wv[tid + 256 * i];
    }
    __syncthreads();
    int r = blockIdx.x * 16 + (tid >> 4);
    int c0 = (tid & 15) << 2;
    const float4* xrow = (const float4*)(X + (size_t)r * D_FEAT);
    float ax = 0.f, ay = 0.f, az = 0.f, aw = 0.f;
    #pragma unroll
    for (int k4 = 0; k4 < 16; ++k4) {
        float4 xv = xrow[k4];
        #pragma unroll
        for (int j = 0; j < 4; ++j) {
            float xs = (j == 0) ? xv.x : (j == 1) ? xv.y : (j == 2) ? xv.z : xv.w;
            const float4 wv = *(const float4*)&Wl[4 * k4 + j][c0];
            ax += xs * wv.x; ay += xs * wv.y; az += xs * wv.z; aw += xs * wv.w;
        }
    }
    union { __half2 h2[2]; uint2 u2; } cvt;
    cvt.h2[0] = __floats2half2_rn(ax, ay);
    cvt.h2[1] = __floats2half2_rn(az, aw);
    *(uint2*)(out + (size_t)r * D_FEAT + c0) = cvt.u2;
}

// layer 2: fp16 input
__global__ __launch_bounds__(256) void k_gemm_f16(const __half* __restrict__ X,
                                                  const float* __restrict__ W,
                                                  __half* __restrict__ out) {
    __shared__ float Wl[64][64];
    int tid = threadIdx.x;
    {
        const float4* Wv = (const float4*)W;
        float4* Wlv = (float4*)&Wl[0][0];
        #pragma unroll
        for (int i = 0; i < 4; ++i) Wlv[tid + 256 * i] = Wv[tid + 256 * i];
    }
    __syncthreads();
    int r = blockIdx.x * 16 + (tid >> 4);
    int c0 = (tid & 15) << 2;
    const __half2* xrow = (const __half2*)(X + (size_t)r * D_FEAT);
    float ax = 0.f, ay = 0.f, az = 0.f, aw = 0.f;
    #pragma unroll
    for (int k4 = 0; k4 < 16; ++k4) {
        float2 lo = __half22float2(xrow[2 * k4]);
        float2 hi = __half22float2(xrow[2 * k4 + 1]);
        #pragma unroll
        for (int j = 0; j < 4; ++j) {
            float xs = (j == 0) ? lo.x : (j == 1) ? lo.y : (j == 2) ? hi.x : hi.y;
            const float4 wv = *(const float4*)&Wl[4 * k4 + j][c0];
            ax += xs * wv.x; ay += xs * wv.y; az += xs * wv.z; aw += xs * wv.w;
        }
    }
    union { __half2 h2[2]; uint2 u2; } cvt;
    cvt.h2[0] = __floats2half2_rn(ax, ay);
    cvt.h2[1] = __floats2half2_rn(az, aw);
    *(uint2*)(out + (size_t)r * D_FEAT + c0) = cvt.u2;
}

// ---------------- aggregation (fp16 rows, f32 accumulate) ----------------

__device__ __forceinline__ float agg_gather_h(const __half* __restrict__ hm,
                                              const int* __restrict__ colsrc,
                                              const float* __restrict__ dinv,
                                              int beg, int deg, int f) {
    float acc = 0.0f;
    for (int base = 0; base < deg; base += 64) {
        int cnt = deg - base; if (cnt > 64) cnt = 64;
        int idx = 0; float w = 0.0f;
        if (f < cnt) { idx = colsrc[beg + base + f]; w = dinv[idx]; }
        int j = 0;
        for (; j + 8 <= cnt; j += 8) {
            int   sj[8];
            float wj[8], vj[8];
            #pragma unroll
            for (int u = 0; u < 8; ++u) {
                sj[u] = __shfl(idx, j + u, 64);
                wj[u] = __shfl(w,   j + u, 64);
            }
            #pragma unroll
            for (int u = 0; u < 8; ++u)
                vj[u] = __half2float(hm[(size_t)sj[u] * D_FEAT + f]);
            #pragma unroll
            for (int u = 0; u < 8; ++u) acc += vj[u] * wj[u];
        }
        for (; j < cnt; ++j) {
            int   s  = __shfl(idx, j, 64);
            float ws = __shfl(w,   j, 64);
            acc += __half2float(hm[(size_t)s * D_FEAT + f]) * ws;
        }
    }
    return acc;
}

__global__ __launch_bounds__(256) void k_agg_relu(const __half* __restrict__ hm,
                                                  const int* __restrict__ rowptr,
                                                  const int* __restrict__ colsrc,
                                                  const float* __restrict__ dinv,
                                                  const float* __restrict__ bias,
                                                  __half* __restrict__ outp) {
    int node = blockIdx.x * 4 + (threadIdx.x >> 6);
    int f = threadIdx.x & 63;
    int beg = rowptr[node];
    int end = rowptr[node + 1];
    float self = __half2float(hm[(size_t)node * D_FEAT + f]);
    float acc = agg_gather_h(hm, colsrc, dinv, beg, end - beg, f);
    float di = dinv[node];
    float v = acc * di + self * (di * di) + bias[f];
    outp[(size_t)node * D_FEAT + f] = __float2half(fmaxf(v, 0.0f));
}

__global__ __launch_bounds__(256) void k_agg2_dot(const __half* __restrict__ hm,
                                                  const int* __restrict__ rowptr,
                                                  const int* __restrict__ colsrc,
                                                  const float* __restrict__ dinv,
                                                  const float* __restrict__ bias,
                                                  const float* __restrict__ Wfc,
                                                  float* __restrict__ partials) {
    __shared__ float red[4];
    int node = blockIdx.x * 4 + (threadIdx.x >> 6);
    int f = threadIdx.x & 63;
    int beg = rowptr[node];
    int end = rowptr[node + 1];
    float self = __half2float(hm[(size_t)node * D_FEAT + f]);
    float acc = agg_gather_h(hm, colsrc, dinv, beg, end - beg, f);
    float di = dinv[node];
    float v = acc * di + self * (di * di) + bias[f];
    float contrib = fmaxf(v, 0.0f) * Wfc[f];
    #pragma unroll
    for (int off = 32; off > 0; off >>= 1) contrib += __shfl_down(contrib, off, 64);
    if ((threadIdx.x & 63) == 0) red[threadIdx.x >> 6] = contrib;
    __syncthreads();
    if (threadIdx.x == 0) partials[blockIdx.x] = red[0] + red[1] + red[2] + red[3];
}

__global__ __launch_bounds__(256) void k_final(const float* __restrict__ partials,
                                               const float* __restrict__ bfc,
                                               float* __restrict__ out) {
    __shared__ float red[4];
    float s = 0.0f;
    for (int i = threadIdx.x; i < AGG_BLOCKS; i += 256) s += partials[i];
    #pragma unroll
    for (int off = 32; off > 0; off >>= 1) s += __shfl_down(s, off, 64);
    if ((threadIdx.x & 63) == 0) red[threadIdx.x >> 6] = s;
    __syncthreads();
    if (threadIdx.x == 0) {
        float t = red[0] + red[1] + red[2] + red[3];
        float z = t / (float)N_NODES + bfc[0];
        out[0] = 1.0f / (1.0f + expf(-z));
    }
}

// ---------------- launcher ----------------

extern "C" void kernel_launch(void* const* d_in, const int* in_sizes, int n_in,
                              void* d_out, int out_size, void* d_ws, size_t ws_size,
                              hipStream_t stream) {
    const float* x   = (const float*)d_in[0];
    const int*   ei  = (const int*)d_in[1];
    const int*   src = ei;               // edge_index[0]
    const int*   dst = ei + N_EDGES;     // edge_index[1]
    const float* W1  = (const float*)d_in[2];
    const float* b1  = (const float*)d_in[3];
    const float* W2  = (const float*)d_in[4];
    const float* b2  = (const float*)d_in[5];
    const float* Wfc = (const float*)d_in[6];
    const float* bfc = (const float*)d_in[7];
    float* out = (float*)d_out;

    char* ws = (char*)d_ws;
    size_t off = 0;
    auto alloc = [&](size_t bytes) -> char* {
        char* p = ws + off;
        off += (bytes + 255) & ~(size_t)255;
        return p;
    };
    int*      cnt      = (int*)alloc((size_t)SCAN_N * 4);
    int*      basex    = (int*)alloc((size_t)SCAN_N * 4);
    int*      spart    = (int*)alloc(256 * 4);
    unsigned* ebuf     = (unsigned*)alloc((size_t)N_EDGES * 4);
    int*      colsrc   = (int*)alloc((size_t)N_EDGES * 4);
    int*      rowptr   = (int*)alloc((size_t)(NBUCKET * 256 + 1) * 4);   // 50177
    float*    dinv     = (float*)alloc((size_t)(NBUCKET * 256) * 4);     // 50176
    float*    partials = (float*)alloc((size_t)AGG_BLOCKS * 4);
    __half*   bufA     = (__half*)alloc((size_t)N_NODES * D_FEAT * 2);
    __half*   bufB     = (__half*)alloc((size_t)N_NODES * D_FEAT * 2);

    // CSR build: coarse partition -> exact LDS grouping
    k_p1hist   <<<P1_BLOCKS, 256, 0, stream>>>(dst, cnt);
    k_sc_part  <<<SCAN_NB,   256, 0, stream>>>(cnt, basex, spart);
    k_sc_tops  <<<1,         256, 0, stream>>>(spart);
    k_sc_add   <<<SCAN_NB,   256, 0, stream>>>(basex, spart);
    k_p1scatter<<<P1_BLOCKS, 256, 0, stream>>>(src, dst, basex, ebuf);
    k_p2group  <<<NBUCKET,   256, 0, stream>>>(ebuf, basex, rowptr, colsrc, dinv);

    // layer 1: hm = x@W1 (fp16) ; h1 = relu(agg(hm) + b1) (fp16)
    k_gemm_f32 <<<GEMM_BLOCKS, 256, 0, stream>>>(x, W1, bufA);
    k_agg_relu <<<AGG_BLOCKS,  256, 0, stream>>>(bufA, rowptr, colsrc, dinv, b1, bufB);

    // layer 2: hm2 = h1@W2 (fp16) ; fused agg + b2 + relu + dot(Wfc) + partial mean
    k_gemm_f16 <<<GEMM_BLOCKS, 256, 0, stream>>>(bufB, W2, bufA);
    k_agg2_dot <<<AGG_BLOCKS,  256, 0, stream>>>(bufA, rowptr, colsrc, dinv, b2, Wfc, partials);

    // final: sigmoid(mean + bfc)
    k_final    <<<1, 256, 0, stream>>>(partials, bfc, out);
}

// Round 7
// 93.307 us; speedup vs baseline: 3.2713x; 1.4911x over previous
//
// GCN2 on MI355X — r6: shuffle-free agg (8 lanes/node, dinv pre-scaled rows in GEMM epilogue),
// scan-free CSR build (fixed-capacity bucket regions + global atomic reservation), u16 colsrc.
#include <hip/hip_runtime.h>
#include <hip/hip_fp16.h>
#include <math.h>

#define N_NODES 50000
#define N_EDGES 800000
#define D_FEAT 64

#define NBUCKET 196            // bucket = dst>>8 ; max 49999>>8 = 195
#define PART_BLOCKS 196
#define PART_EPB 4096          // 196*4096 = 802816 >= E
#define BCAP 6144              // per-bucket capacity; mean 4096, sigma 64 -> 32 sigma margin

#define GEMM_BLOCKS (N_NODES / 16)          // 3125 exact
#define AGG_BLOCKS 1568                     // 1568*32 = 50176 node slots (>= 50000)
#define N_PAD (NBUCKET * 256)               // 50176

// ---------------- CSR build: 3 kernels, no scan ----------------

__global__ __launch_bounds__(256) void k_zero(int* __restrict__ gcount) {
    if (threadIdx.x < NBUCKET) gcount[threadIdx.x] = 0;
}

// single pass: stage edges in LDS, count, reserve region space, scatter packed edges
__global__ __launch_bounds__(256) void k_part(const int* __restrict__ src,
                                              const int* __restrict__ dst,
                                              int* __restrict__ gcount,
                                              unsigned* __restrict__ ebuf) {
    __shared__ unsigned eloc[PART_EPB];
    __shared__ int cnt[NBUCKET];
    int tid = threadIdx.x;
    for (int i = tid; i < NBUCKET; i += 256) cnt[i] = 0;
    __syncthreads();
    int e0 = blockIdx.x * PART_EPB;
    int n = N_EDGES - e0; if (n > PART_EPB) n = PART_EPB;
    for (int k = tid; k < n; k += 256) {
        int e = e0 + k;
        int d = dst[e];
        eloc[k] = (unsigned)src[e] | ((unsigned)(d & 255) << 16) | ((unsigned)(d >> 8) << 24);
        atomicAdd(&cnt[d >> 8], 1);
    }
    __syncthreads();
    for (int i = tid; i < NBUCKET; i += 256)
        cnt[i] = atomicAdd(&gcount[i], cnt[i]);      // cnt[i] := bucket-local base
    __syncthreads();
    for (int k = tid; k < n; k += 256) {
        unsigned p = eloc[k];
        int b = p >> 24;
        int slot = atomicAdd(&cnt[b], 1);
        if (slot < BCAP) ebuf[(size_t)b * BCAP + slot] = p;
    }
}

// per bucket: exact grouping in LDS -> rowbeg/rowdeg/dinv/colsrc(u16)
__global__ __launch_bounds__(256) void k_p2group(const unsigned* __restrict__ ebuf,
                                                 const int* __restrict__ gcount,
                                                 int* __restrict__ rowbeg,
                                                 int* __restrict__ rowdeg,
                                                 ushort* __restrict__ colsrc,
                                                 float* __restrict__ dinv) {
    __shared__ unsigned eloc[BCAP];
    __shared__ int hist[256];
    __shared__ int sh[256];
    int tid = threadIdx.x;
    int b = blockIdx.x;
    int cnt = gcount[b]; if (cnt > BCAP) cnt = BCAP;
    hist[tid] = 0;
    __syncthreads();
    for (int i = tid; i < cnt; i += 256) {
        unsigned p = ebuf[(size_t)b * BCAP + i];
        eloc[i] = p;
        atomicAdd(&hist[(p >> 16) & 255], 1);
    }
    __syncthreads();
    int v = hist[tid];                    // global in-degree of node b*256+tid
    sh[tid] = v;
    __syncthreads();
    #pragma unroll
    for (int off = 1; off < 256; off <<= 1) {
        int t = (tid >= off) ? sh[tid - off] : 0;
        __syncthreads();
        sh[tid] += t;
        __syncthreads();
    }
    int binoff = sh[tid] - v;             // exclusive scan
    int node = b * 256 + tid;
    rowbeg[node] = b * BCAP + binoff;
    rowdeg[node] = v;
    dinv[node] = rsqrtf((float)(v + 1));  // +1 self loop
    hist[tid] = binoff;                   // reuse as bucket-local cursor
    __syncthreads();
    for (int i = tid; i < cnt; i += 256) {
        unsigned p = eloc[i];
        int slot = b * BCAP + atomicAdd(&hist[(p >> 16) & 255], 1);
        colsrc[slot] = (ushort)(p & 0xFFFFu);
    }
}

// ---------------- GEMMs with dinv-scaled fp16 epilogue ----------------

__global__ __launch_bounds__(256) void k_gemm_f32(const float* __restrict__ X,
                                                  const float* __restrict__ W,
                                                  const float* __restrict__ dinv,
                                                  __half* __restrict__ out) {
    __shared__ float Wl[64][64];
    int tid = threadIdx.x;
    {
        const float4* Wv = (const float4*)W;
        float4* Wlv = (float4*)&Wl[0][0];
        #pragma unroll
        for (int i = 0; i < 4; ++i) Wlv[tid + 256 * i] = Wv[tid + 256 * i];
    }
    __syncthreads();
    int r = blockIdx.x * 16 + (tid >> 4);
    int c0 = (tid & 15) << 2;
    const float4* xrow = (const float4*)(X + (size_t)r * D_FEAT);
    float ax = 0.f, ay = 0.f, az = 0.f, aw = 0.f;
    #pragma unroll
    for (int k4 = 0; k4 < 16; ++k4) {
        float4 xv = xrow[k4];
        #pragma unroll
        for (int j = 0; j < 4; ++j) {
            float xs = (j == 0) ? xv.x : (j == 1) ? xv.y : (j == 2) ? xv.z : xv.w;
            const float4 wv = *(const float4*)&Wl[4 * k4 + j][c0];
            ax += xs * wv.x; ay += xs * wv.y; az += xs * wv.z; aw += xs * wv.w;
        }
    }
    float sc = dinv[r];
    union { __half2 h2[2]; uint2 u2; } cvt;
    cvt.h2[0] = __floats2half2_rn(ax * sc, ay * sc);
    cvt.h2[1] = __floats2half2_rn(az * sc, aw * sc);
    *(uint2*)(out + (size_t)r * D_FEAT + c0) = cvt.u2;
}

__global__ __launch_bounds__(256) void k_gemm_f16(const __half* __restrict__ X,
                                                  const float* __restrict__ W,
                                                  const float* __restrict__ dinv,
                                                  __half* __restrict__ out) {
    __shared__ float Wl[64][64];
    int tid = threadIdx.x;
    {
        const float4* Wv = (const float4*)W;
        float4* Wlv = (float4*)&Wl[0][0];
        #pragma unroll
        for (int i = 0; i < 4; ++i) Wlv[tid + 256 * i] = Wv[tid + 256 * i];
    }
    __syncthreads();
    int r = blockIdx.x * 16 + (tid >> 4);
    int c0 = (tid & 15) << 2;
    const __half2* xrow = (const __half2*)(X + (size_t)r * D_FEAT);
    float ax = 0.f, ay = 0.f, az = 0.f, aw = 0.f;
    #pragma unroll
    for (int k4 = 0; k4 < 16; ++k4) {
        float2 lo = __half22float2(xrow[2 * k4]);
        float2 hi = __half22float2(xrow[2 * k4 + 1]);
        #pragma unroll
        for (int j = 0; j < 4; ++j) {
            float xs = (j == 0) ? lo.x : (j == 1) ? lo.y : (j == 2) ? hi.x : hi.y;
            const float4 wv = *(const float4*)&Wl[4 * k4 + j][c0];
            ax += xs * wv.x; ay += xs * wv.y; az += xs * wv.z; aw += xs * wv.w;
        }
    }
    float sc = dinv[r];
    union { __half2 h2[2]; uint2 u2; } cvt;
    cvt.h2[0] = __floats2half2_rn(ax * sc, ay * sc);
    cvt.h2[1] = __floats2half2_rn(az * sc, aw * sc);
    *(uint2*)(out + (size_t)r * D_FEAT + c0) = cvt.u2;
}

// ---------------- aggregation: 8 lanes per node, shuffle-free edge loop ----------------
// hm rows are pre-scaled by dinv (hm'). out = di*(sum_nbr hm'[s] + hm'[node]) + bias.

__device__ __forceinline__ void addh8(float acc[8], uint4 r) {
    union { uint4 u; __half2 h[4]; } c; c.u = r;
    #pragma unroll
    for (int i = 0; i < 4; ++i) {
        float2 f = __half22float2(c.h[i]);
        acc[2 * i]     += f.x;
        acc[2 * i + 1] += f.y;
    }
}

__device__ __forceinline__ void agg_core(const __half* __restrict__ hm,
                                         const ushort* __restrict__ colsrc,
                                         int beg, int deg, int o, float acc[8]) {
    const uint4* hv = (const uint4*)hm;     // row = 8 uint4 (128 B)
    int j = 0;
    for (; j + 4 <= deg; j += 4) {
        int s0 = colsrc[beg + j];
        int s1 = colsrc[beg + j + 1];
        int s2 = colsrc[beg + j + 2];
        int s3 = colsrc[beg + j + 3];
        uint4 r0 = hv[(size_t)s0 * 8 + o];
        uint4 r1 = hv[(size_t)s1 * 8 + o];
        uint4 r2 = hv[(size_t)s2 * 8 + o];
        uint4 r3 = hv[(size_t)s3 * 8 + o];
        addh8(acc, r0); addh8(acc, r1); addh8(acc, r2); addh8(acc, r3);
    }
    for (; j < deg; ++j) {
        int s = colsrc[beg + j];
        addh8(acc, hv[(size_t)s * 8 + o]);
    }
}

__global__ __launch_bounds__(256) void k_agg_relu(const __half* __restrict__ hm,
                                                  const int* __restrict__ rowbeg,
                                                  const int* __restrict__ rowdeg,
                                                  const ushort* __restrict__ colsrc,
                                                  const float* __restrict__ dinv,
                                                  const float* __restrict__ bias,
                                                  __half* __restrict__ outp) {
    int lane = threadIdx.x & 63;
    int wid = threadIdx.x >> 6;
    int node = (blockIdx.x * 4 + wid) * 8 + (lane >> 3);   // 8 node slots per wave
    int o = lane & 7;                                      // feature octet
    bool valid = node < N_NODES;
    float acc[8];
    #pragma unroll
    for (int i = 0; i < 8; ++i) acc[i] = 0.f;
    if (valid) {
        const uint4* hv = (const uint4*)hm;
        addh8(acc, hv[(size_t)node * 8 + o]);              // self (pre-scaled)
        agg_core(hm, colsrc, rowbeg[node], rowdeg[node], o, acc);
        float di = dinv[node];
        const float4* b4 = (const float4*)bias;
        float4 bl = b4[o * 2], bh = b4[o * 2 + 1];
        union { uint4 u; __half2 h[4]; } st;
        st.h[0] = __floats2half2_rn(fmaxf(di * acc[0] + bl.x, 0.f), fmaxf(di * acc[1] + bl.y, 0.f));
        st.h[1] = __floats2half2_rn(fmaxf(di * acc[2] + bl.z, 0.f), fmaxf(di * acc[3] + bl.w, 0.f));
        st.h[2] = __floats2half2_rn(fmaxf(di * acc[4] + bh.x, 0.f), fmaxf(di * acc[5] + bh.y, 0.f));
        st.h[3] = __floats2half2_rn(fmaxf(di * acc[6] + bh.z, 0.f), fmaxf(di * acc[7] + bh.w, 0.f));
        *(uint4*)(outp + (size_t)node * D_FEAT + o * 8) = st.u;
    }
}

__global__ __launch_bounds__(256) void k_agg2_dot(const __half* __restrict__ hm,
                                                  const int* __restrict__ rowbeg,
                                                  const int* __restrict__ rowdeg,
                                                  const ushort* __restrict__ colsrc,
                                                  const float* __restrict__ dinv,
                                                  const float* __restrict__ bias,
                                                  const float* __restrict__ Wfc,
                                                  float* __restrict__ partials) {
    __shared__ float red[4];
    int lane = threadIdx.x & 63;
    int wid = threadIdx.x >> 6;
    int node = (blockIdx.x * 4 + wid) * 8 + (lane >> 3);
    int o = lane & 7;
    bool valid = node < N_NODES;
    float acc[8];
    #pragma unroll
    for (int i = 0; i < 8; ++i) acc[i] = 0.f;
    float s = 0.f;
    if (valid) {
        const uint4* hv = (const uint4*)hm;
        addh8(acc, hv[(size_t)node * 8 + o]);
        agg_core(hm, colsrc, rowbeg[node], rowdeg[node], o, acc);
        float di = dinv[node];
        const float4* b4 = (const float4*)bias;
        const float4* w4 = (const float4*)Wfc;
        float4 bl = b4[o * 2], bh = b4[o * 2 + 1];
        float4 wl = w4[o * 2], wh = w4[o * 2 + 1];
        s  = fmaxf(di * acc[0] + bl.x, 0.f) * wl.x;
        s += fmaxf(di * acc[1] + bl.y, 0.f) * wl.y;
        s += fmaxf(di * acc[2] + bl.z, 0.f) * wl.z;
        s += fmaxf(di * acc[3] + bl.w, 0.f) * wl.w;
        s += fmaxf(di * acc[4] + bh.x, 0.f) * wh.x;
        s += fmaxf(di * acc[5] + bh.y, 0.f) * wh.y;
        s += fmaxf(di * acc[6] + bh.z, 0.f) * wh.z;
        s += fmaxf(di * acc[7] + bh.w, 0.f) * wh.w;
    }
    // convergent 64-lane butterfly: every lane's s counted once
    #pragma unroll
    for (int m = 1; m < 64; m <<= 1) s += __shfl_xor(s, m, 64);
    if (lane == 0) red[wid] = s;
    __syncthreads();
    if (threadIdx.x == 0) partials[blockIdx.x] = red[0] + red[1] + red[2] + red[3];
}

__global__ __launch_bounds__(256) void k_final(const float* __restrict__ partials,
                                               const float* __restrict__ bfc,
                                               float* __restrict__ out) {
    __shared__ float red[4];
    float s = 0.0f;
    for (int i = threadIdx.x; i < AGG_BLOCKS; i += 256) s += partials[i];
    #pragma unroll
    for (int off = 32; off > 0; off >>= 1) s += __shfl_down(s, off, 64);
    if ((threadIdx.x & 63) == 0) red[threadIdx.x >> 6] = s;
    __syncthreads();
    if (threadIdx.x == 0) {
        float t = red[0] + red[1] + red[2] + red[3];
        float z = t / (float)N_NODES + bfc[0];
        out[0] = 1.0f / (1.0f + expf(-z));
    }
}

// ---------------- launcher ----------------

extern "C" void kernel_launch(void* const* d_in, const int* in_sizes, int n_in,
                              void* d_out, int out_size, void* d_ws, size_t ws_size,
                              hipStream_t stream) {
    const float* x   = (const float*)d_in[0];
    const int*   ei  = (const int*)d_in[1];
    const int*   src = ei;               // edge_index[0]
    const int*   dst = ei + N_EDGES;     // edge_index[1]
    const float* W1  = (const float*)d_in[2];
    const float* b1  = (const float*)d_in[3];
    const float* W2  = (const float*)d_in[4];
    const float* b2  = (const float*)d_in[5];
    const float* Wfc = (const float*)d_in[6];
    const float* bfc = (const float*)d_in[7];
    float* out = (float*)d_out;

    char* ws = (char*)d_ws;
    size_t off = 0;
    auto alloc = [&](size_t bytes) -> char* {
        char* p = ws + off;
        off += (bytes + 255) & ~(size_t)255;
        return p;
    };
    int*      gcount   = (int*)alloc((size_t)NBUCKET * 4);
    unsigned* ebuf     = (unsigned*)alloc((size_t)NBUCKET * BCAP * 4);   // 4.8 MB
    ushort*   colsrc   = (ushort*)alloc((size_t)NBUCKET * BCAP * 2);     // 2.4 MB
    int*      rowbeg   = (int*)alloc((size_t)N_PAD * 4);
    int*      rowdeg   = (int*)alloc((size_t)N_PAD * 4);
    float*    dinv     = (float*)alloc((size_t)N_PAD * 4);
    float*    partials = (float*)alloc((size_t)AGG_BLOCKS * 4);
    __half*   bufA     = (__half*)alloc((size_t)N_NODES * D_FEAT * 2);
    __half*   bufB     = (__half*)alloc((size_t)N_NODES * D_FEAT * 2);

    // CSR build: zero counters -> single-pass bucket partition -> exact LDS grouping
    k_zero     <<<1,           256, 0, stream>>>(gcount);
    k_part     <<<PART_BLOCKS, 256, 0, stream>>>(src, dst, gcount, ebuf);
    k_p2group  <<<NBUCKET,     256, 0, stream>>>(ebuf, gcount, rowbeg, rowdeg, colsrc, dinv);

    // layer 1: hm' = (x@W1)*dinv (fp16) ; h1 = relu(di*(sum+self') + b1) (fp16)
    k_gemm_f32 <<<GEMM_BLOCKS, 256, 0, stream>>>(x, W1, dinv, bufA);
    k_agg_relu <<<AGG_BLOCKS,  256, 0, stream>>>(bufA, rowbeg, rowdeg, colsrc, dinv, b1, bufB);

    // layer 2: hm2' = (h1@W2)*dinv (fp16) ; fused agg + b2 + relu + dot(Wfc) + partial mean
    k_gemm_f16 <<<GEMM_BLOCKS, 256, 0, stream>>>(bufB, W2, dinv, bufA);
    k_agg2_dot <<<AGG_BLOCKS,  256, 0, stream>>>(bufA, rowbeg, rowdeg, colsrc, dinv, b2, Wfc, partials);

    // final: sigmoid(mean + bfc)
    k_final    <<<1, 256, 0, stream>>>(partials, bfc, out);
}

// Round 8
// 88.643 us; speedup vs baseline: 3.4434x; 1.0526x over previous
//
// GCN2 on MI355X — r7: fuse layer-2 GEMM into agg1 (in-register 8-lane shuffle GEMM),
// 8-deep gather MLP unroll. 7 kernels total.
#include <hip/hip_runtime.h>
#include <hip/hip_fp16.h>
#include <math.h>

#define N_NODES 50000
#define N_EDGES 800000
#define D_FEAT 64

#define NBUCKET 196            // bucket = dst>>8 ; max 49999>>8 = 195
#define PART_BLOCKS 196
#define PART_EPB 4096          // 196*4096 = 802816 >= E
#define BCAP 6144              // per-bucket capacity; mean 4096, sigma 64

#define GEMM_BLOCKS (N_NODES / 16)          // 3125 exact
#define AGG_BLOCKS 1568                     // 1568*32 = 50176 node slots (>= 50000)
#define N_PAD (NBUCKET * 256)               // 50176

// ---------------- CSR build: 3 kernels, no scan ----------------

__global__ __launch_bounds__(256) void k_zero(int* __restrict__ gcount) {
    if (threadIdx.x < NBUCKET) gcount[threadIdx.x] = 0;
}

__global__ __launch_bounds__(256) void k_part(const int* __restrict__ src,
                                              const int* __restrict__ dst,
                                              int* __restrict__ gcount,
                                              unsigned* __restrict__ ebuf) {
    __shared__ unsigned eloc[PART_EPB];
    __shared__ int cnt[NBUCKET];
    int tid = threadIdx.x;
    for (int i = tid; i < NBUCKET; i += 256) cnt[i] = 0;
    __syncthreads();
    int e0 = blockIdx.x * PART_EPB;
    int n = N_EDGES - e0; if (n > PART_EPB) n = PART_EPB;
    for (int k = tid; k < n; k += 256) {
        int e = e0 + k;
        int d = dst[e];
        eloc[k] = (unsigned)src[e] | ((unsigned)(d & 255) << 16) | ((unsigned)(d >> 8) << 24);
        atomicAdd(&cnt[d >> 8], 1);
    }
    __syncthreads();
    for (int i = tid; i < NBUCKET; i += 256)
        cnt[i] = atomicAdd(&gcount[i], cnt[i]);      // cnt[i] := bucket-local base
    __syncthreads();
    for (int k = tid; k < n; k += 256) {
        unsigned p = eloc[k];
        int b = p >> 24;
        int slot = atomicAdd(&cnt[b], 1);
        if (slot < BCAP) ebuf[(size_t)b * BCAP + slot] = p;
    }
}

__global__ __launch_bounds__(256) void k_p2group(const unsigned* __restrict__ ebuf,
                                                 const int* __restrict__ gcount,
                                                 int* __restrict__ rowbeg,
                                                 int* __restrict__ rowdeg,
                                                 ushort* __restrict__ colsrc,
                                                 float* __restrict__ dinv) {
    __shared__ unsigned eloc[BCAP];
    __shared__ int hist[256];
    __shared__ int sh[256];
    int tid = threadIdx.x;
    int b = blockIdx.x;
    int cnt = gcount[b]; if (cnt > BCAP) cnt = BCAP;
    hist[tid] = 0;
    __syncthreads();
    for (int i = tid; i < cnt; i += 256) {
        unsigned p = ebuf[(size_t)b * BCAP + i];
        eloc[i] = p;
        atomicAdd(&hist[(p >> 16) & 255], 1);
    }
    __syncthreads();
    int v = hist[tid];
    sh[tid] = v;
    __syncthreads();
    #pragma unroll
    for (int off = 1; off < 256; off <<= 1) {
        int t = (tid >= off) ? sh[tid - off] : 0;
        __syncthreads();
        sh[tid] += t;
        __syncthreads();
    }
    int binoff = sh[tid] - v;
    int node = b * 256 + tid;
    rowbeg[node] = b * BCAP + binoff;
    rowdeg[node] = v;
    dinv[node] = rsqrtf((float)(v + 1));
    hist[tid] = binoff;
    __syncthreads();
    for (int i = tid; i < cnt; i += 256) {
        unsigned p = eloc[i];
        int slot = b * BCAP + atomicAdd(&hist[(p >> 16) & 255], 1);
        colsrc[slot] = (ushort)(p & 0xFFFFu);
    }
}

// ---------------- GEMM layer 1: hm1' = (x @ W1) * dinv, fp16 ----------------

__global__ __launch_bounds__(256) void k_gemm_f32(const float* __restrict__ X,
                                                  const float* __restrict__ W,
                                                  const float* __restrict__ dinv,
                                                  __half* __restrict__ out) {
    __shared__ float Wl[64][64];
    int tid = threadIdx.x;
    {
        const float4* Wv = (const float4*)W;
        float4* Wlv = (float4*)&Wl[0][0];
        #pragma unroll
        for (int i = 0; i < 4; ++i) Wlv[tid + 256 * i] = Wv[tid + 256 * i];
    }
    __syncthreads();
    int r = blockIdx.x * 16 + (tid >> 4);
    int c0 = (tid & 15) << 2;
    const float4* xrow = (const float4*)(X + (size_t)r * D_FEAT);
    float ax = 0.f, ay = 0.f, az = 0.f, aw = 0.f;
    #pragma unroll
    for (int k4 = 0; k4 < 16; ++k4) {
        float4 xv = xrow[k4];
        #pragma unroll
        for (int j = 0; j < 4; ++j) {
            float xs = (j == 0) ? xv.x : (j == 1) ? xv.y : (j == 2) ? xv.z : xv.w;
            const float4 wv = *(const float4*)&Wl[4 * k4 + j][c0];
            ax += xs * wv.x; ay += xs * wv.y; az += xs * wv.z; aw += xs * wv.w;
        }
    }
    float sc = dinv[r];
    union { __half2 h2[2]; uint2 u2; } cvt;
    cvt.h2[0] = __floats2half2_rn(ax * sc, ay * sc);
    cvt.h2[1] = __floats2half2_rn(az * sc, aw * sc);
    *(uint2*)(out + (size_t)r * D_FEAT + c0) = cvt.u2;
}

// ---------------- aggregation core: 8 lanes/node, 8-deep MLP ----------------

__device__ __forceinline__ void addh8(float acc[8], uint4 r) {
    union { uint4 u; __half2 h[4]; } c; c.u = r;
    #pragma unroll
    for (int i = 0; i < 4; ++i) {
        float2 f = __half22float2(c.h[i]);
        acc[2 * i]     += f.x;
        acc[2 * i + 1] += f.y;
    }
}

__device__ __forceinline__ void agg_core(const __half* __restrict__ hm,
                                         const ushort* __restrict__ colsrc,
                                         int beg, int deg, int o, float acc[8]) {
    const uint4* hv = (const uint4*)hm;     // row = 8 uint4 (128 B)
    int j = 0;
    for (; j + 8 <= deg; j += 8) {
        int s[8]; uint4 r[8];
        #pragma unroll
        for (int u = 0; u < 8; ++u) s[u] = colsrc[beg + j + u];
        #pragma unroll
        for (int u = 0; u < 8; ++u) r[u] = hv[(size_t)s[u] * 8 + o];
        #pragma unroll
        for (int u = 0; u < 8; ++u) addh8(acc, r[u]);
    }
    if (j + 4 <= deg) {
        int s[4]; uint4 r[4];
        #pragma unroll
        for (int u = 0; u < 4; ++u) s[u] = colsrc[beg + j + u];
        #pragma unroll
        for (int u = 0; u < 4; ++u) r[u] = hv[(size_t)s[u] * 8 + o];
        #pragma unroll
        for (int u = 0; u < 4; ++u) addh8(acc, r[u]);
        j += 4;
    }
    for (; j < deg; ++j) {
        int s = colsrc[beg + j];
        addh8(acc, hv[(size_t)s * 8 + o]);
    }
}

// ---- layer-1 agg + ReLU + fused layer-2 GEMM: hm2' = (relu(agg)+b1)@W2 * dinv ----

__global__ __launch_bounds__(256) void k_agg1_g2(const __half* __restrict__ hm,
                                                 const int* __restrict__ rowbeg,
                                                 const int* __restrict__ rowdeg,
                                                 const ushort* __restrict__ colsrc,
                                                 const float* __restrict__ dinv,
                                                 const float* __restrict__ b1,
                                                 const float* __restrict__ W2,
                                                 __half* __restrict__ outp) {
    __shared__ float Wl[64][64];
    {
        const float4* Wv = (const float4*)W2;
        float4* Wlv = (float4*)&Wl[0][0];
        #pragma unroll
        for (int i = 0; i < 4; ++i) Wlv[threadIdx.x + 256 * i] = Wv[threadIdx.x + 256 * i];
    }
    __syncthreads();
    int lane = threadIdx.x & 63;
    int wid = threadIdx.x >> 6;
    int node = (blockIdx.x * 4 + wid) * 8 + (lane >> 3);
    int o = lane & 7;
    bool valid = node < N_NODES;
    if (valid) {
        float acc[8];
        #pragma unroll
        for (int i = 0; i < 8; ++i) acc[i] = 0.f;
        const uint4* hv = (const uint4*)hm;
        addh8(acc, hv[(size_t)node * 8 + o]);               // self (pre-scaled)
        agg_core(hm, colsrc, rowbeg[node], rowdeg[node], o, acc);
        float di = dinv[node];
        const float4* b4 = (const float4*)b1;
        float4 bl = b4[o * 2], bh = b4[o * 2 + 1];
        float h1[8];
        h1[0] = fmaxf(di * acc[0] + bl.x, 0.f);
        h1[1] = fmaxf(di * acc[1] + bl.y, 0.f);
        h1[2] = fmaxf(di * acc[2] + bl.z, 0.f);
        h1[3] = fmaxf(di * acc[3] + bl.w, 0.f);
        h1[4] = fmaxf(di * acc[4] + bh.x, 0.f);
        h1[5] = fmaxf(di * acc[5] + bh.y, 0.f);
        h1[6] = fmaxf(di * acc[6] + bh.z, 0.f);
        h1[7] = fmaxf(di * acc[7] + bh.w, 0.f);
        // in-register GEMM: oa[c] = sum_k h1[k] * W2[k][o*8+c]
        float oa[8];
        #pragma unroll
        for (int i = 0; i < 8; ++i) oa[i] = 0.f;
        int gbase = lane & 56;                              // group base lane
        #pragma unroll
        for (int g = 0; g < 8; ++g) {
            #pragma unroll
            for (int j = 0; j < 8; ++j) {
                float hk = __shfl(h1[j], gbase | g, 64);    // h1[g*8+j] of this node
                const float4 w0 = *(const float4*)&Wl[g * 8 + j][o * 8];
                const float4 w1 = *(const float4*)&Wl[g * 8 + j][o * 8 + 4];
                oa[0] += hk * w0.x; oa[1] += hk * w0.y;
                oa[2] += hk * w0.z; oa[3] += hk * w0.w;
                oa[4] += hk * w1.x; oa[5] += hk * w1.y;
                oa[6] += hk * w1.z; oa[7] += hk * w1.w;
            }
        }
        union { uint4 u; __half2 h[4]; } st;
        st.h[0] = __floats2half2_rn(oa[0] * di, oa[1] * di);
        st.h[1] = __floats2half2_rn(oa[2] * di, oa[3] * di);
        st.h[2] = __floats2half2_rn(oa[4] * di, oa[5] * di);
        st.h[3] = __floats2half2_rn(oa[6] * di, oa[7] * di);
        *(uint4*)(outp + (size_t)node * D_FEAT + o * 8) = st.u;
    }
}

// ---- layer-2 agg + b2 + ReLU + dot(Wfc) + block partial sum ----

__global__ __launch_bounds__(256) void k_agg2_dot(const __half* __restrict__ hm,
                                                  const int* __restrict__ rowbeg,
                                                  const int* __restrict__ rowdeg,
                                                  const ushort* __restrict__ colsrc,
                                                  const float* __restrict__ dinv,
                                                  const float* __restrict__ bias,
                                                  const float* __restrict__ Wfc,
                                                  float* __restrict__ partials) {
    __shared__ float red[4];
    int lane = threadIdx.x & 63;
    int wid = threadIdx.x >> 6;
    int node = (blockIdx.x * 4 + wid) * 8 + (lane >> 3);
    int o = lane & 7;
    bool valid = node < N_NODES;
    float s = 0.f;
    if (valid) {
        float acc[8];
        #pragma unroll
        for (int i = 0; i < 8; ++i) acc[i] = 0.f;
        const uint4* hv = (const uint4*)hm;
        addh8(acc, hv[(size_t)node * 8 + o]);
        agg_core(hm, colsrc, rowbeg[node], rowdeg[node], o, acc);
        float di = dinv[node];
        const float4* b4 = (const float4*)bias;
        const float4* w4 = (const float4*)Wfc;
        float4 bl = b4[o * 2], bh = b4[o * 2 + 1];
        float4 wl = w4[o * 2], wh = w4[o * 2 + 1];
        s  = fmaxf(di * acc[0] + bl.x, 0.f) * wl.x;
        s += fmaxf(di * acc[1] + bl.y, 0.f) * wl.y;
        s += fmaxf(di * acc[2] + bl.z, 0.f) * wl.z;
        s += fmaxf(di * acc[3] + bl.w, 0.f) * wl.w;
        s += fmaxf(di * acc[4] + bh.x, 0.f) * wh.x;
        s += fmaxf(di * acc[5] + bh.y, 0.f) * wh.y;
        s += fmaxf(di * acc[6] + bh.z, 0.f) * wh.z;
        s += fmaxf(di * acc[7] + bh.w, 0.f) * wh.w;
    }
    #pragma unroll
    for (int m = 1; m < 64; m <<= 1) s += __shfl_xor(s, m, 64);
    if (lane == 0) red[wid] = s;
    __syncthreads();
    if (threadIdx.x == 0) partials[blockIdx.x] = red[0] + red[1] + red[2] + red[3];
}

__global__ __launch_bounds__(256) void k_final(const float* __restrict__ partials,
                                               const float* __restrict__ bfc,
                                               float* __restrict__ out) {
    __shared__ float red[4];
    float s = 0.0f;
    for (int i = threadIdx.x; i < AGG_BLOCKS; i += 256) s += partials[i];
    #pragma unroll
    for (int off = 32; off > 0; off >>= 1) s += __shfl_down(s, off, 64);
    if ((threadIdx.x & 63) == 0) red[threadIdx.x >> 6] = s;
    __syncthreads();
    if (threadIdx.x == 0) {
        float t = red[0] + red[1] + red[2] + red[3];
        float z = t / (float)N_NODES + bfc[0];
        out[0] = 1.0f / (1.0f + expf(-z));
    }
}

// ---------------- launcher ----------------

extern "C" void kernel_launch(void* const* d_in, const int* in_sizes, int n_in,
                              void* d_out, int out_size, void* d_ws, size_t ws_size,
                              hipStream_t stream) {
    const float* x   = (const float*)d_in[0];
    const int*   ei  = (const int*)d_in[1];
    const int*   src = ei;               // edge_index[0]
    const int*   dst = ei + N_EDGES;     // edge_index[1]
    const float* W1  = (const float*)d_in[2];
    const float* b1  = (const float*)d_in[3];
    const float* W2  = (const float*)d_in[4];
    const float* b2  = (const float*)d_in[5];
    const float* Wfc = (const float*)d_in[6];
    const float* bfc = (const float*)d_in[7];
    float* out = (float*)d_out;

    char* ws = (char*)d_ws;
    size_t off = 0;
    auto alloc = [&](size_t bytes) -> char* {
        char* p = ws + off;
        off += (bytes + 255) & ~(size_t)255;
        return p;
    };
    int*      gcount   = (int*)alloc((size_t)NBUCKET * 4);
    unsigned* ebuf     = (unsigned*)alloc((size_t)NBUCKET * BCAP * 4);   // 4.8 MB
    ushort*   colsrc   = (ushort*)alloc((size_t)NBUCKET * BCAP * 2);     // 2.4 MB
    int*      rowbeg   = (int*)alloc((size_t)N_PAD * 4);
    int*      rowdeg   = (int*)alloc((size_t)N_PAD * 4);
    float*    dinv     = (float*)alloc((size_t)N_PAD * 4);
    float*    partials = (float*)alloc((size_t)AGG_BLOCKS * 4);
    __half*   bufA     = (__half*)alloc((size_t)N_NODES * D_FEAT * 2);
    __half*   bufB     = (__half*)alloc((size_t)N_NODES * D_FEAT * 2);

    // CSR build
    k_zero     <<<1,           256, 0, stream>>>(gcount);
    k_part     <<<PART_BLOCKS, 256, 0, stream>>>(src, dst, gcount, ebuf);
    k_p2group  <<<NBUCKET,     256, 0, stream>>>(ebuf, gcount, rowbeg, rowdeg, colsrc, dinv);

    // layer 1 GEMM: hm1' = (x@W1)*dinv (fp16)
    k_gemm_f32 <<<GEMM_BLOCKS, 256, 0, stream>>>(x, W1, dinv, bufA);

    // layer-1 agg + relu + fused layer-2 GEMM: hm2' = (relu(di*sum+b1)@W2)*dinv
    k_agg1_g2  <<<AGG_BLOCKS,  256, 0, stream>>>(bufA, rowbeg, rowdeg, colsrc, dinv, b1, W2, bufB);

    // layer-2 agg + b2 + relu + dot(Wfc) + partial mean
    k_agg2_dot <<<AGG_BLOCKS,  256, 0, stream>>>(bufB, rowbeg, rowdeg, colsrc, dinv, b2, Wfc, partials);

    // final: sigmoid(mean + bfc)
    k_final    <<<1, 256, 0, stream>>>(partials, bfc, out);
}